// Round 4
// baseline (135.810 us; speedup 1.0000x reference)
//
#include <hip/hip_runtime.h>
#include <hip/hip_bf16.h>
#include <stdint.h>
#include <stddef.h>

// DistanceNetwork: sims[n,b] = dot(support[n], input[b]) * rsqrt(||support[n]||^2) * rsqrt(||input||_F^2)
//   support_set: [8192, 1024] fp32   input_image: [2048, 1024] fp32   out: [8192, 2048] fp32
#define M_DIM 8192
#define N_DIM 2048
#define K_DIM 1024

// R4: 256x256, 8-phase, BALANCED prefetch pipeline. Each phase = one
// (k-step, mi-half) quadrant: 16 MFMA + exactly 6 ds_read_b128 prefetch
// (4 A + 2 B) -> LDS pipe 576 cyc < MFMA 614 cyc every phase (R3 had a
// 1150-cyc LOADB-burst phase). Uniform VMW(4) per phase; 2 gloads/phase.
#define BM 256
#define BN 256
#define BK 64
#define NKT (K_DIM / BK)  // 16 K-tiles
#define NITER (NKT / 2)   // 8 iterations (7 full + 1 tail)

typedef __attribute__((ext_vector_type(8))) short short8;   // 8 bf16 = 4 VGPRs
typedef __attribute__((ext_vector_type(4))) float float4v;  // MFMA C/D

// fp32 -> bf16 RNE
static __device__ __forceinline__ unsigned short f2bf(float x) {
  union { float f; unsigned u; } c; c.f = x;
  return (unsigned short)((c.u + 0x7FFFu + ((c.u >> 16) & 1u)) >> 16);
}

#define GLOAD_LDS16(g, l)                                           \
  __builtin_amdgcn_global_load_lds(                                 \
      (const __attribute__((address_space(1))) void*)(g),           \
      (__attribute__((address_space(3))) void*)(l), 16, 0, 0)

// ---------------- fused prep ----------------
// wave-per-row. Blocks [0,2048): support rows 4*blk+wave -> Sb + smag.
// Blocks [2048,2560): input rows -> Ib + partials.
__global__ __launch_bounds__(256) void prep(
    const float* __restrict__ S, const float* __restrict__ I,
    unsigned short* __restrict__ Sb, unsigned short* __restrict__ Ib,
    float* __restrict__ smag, float* __restrict__ partials) {
  const int t = threadIdx.x;
  const int lane = t & 63;
  const int wave = t >> 6;
  const int blk = blockIdx.x;
  const bool isS = blk < 2048;
  const int row = (isS ? blk : blk - 2048) * 4 + wave;
  const float* src = (isS ? S : I) + (size_t)row * K_DIM;
  unsigned short* dst = (isS ? Sb : Ib) + (size_t)row * K_DIM;

  float ss = 0.f;
#pragma unroll
  for (int i = 0; i < 4; ++i) {
    const float4 v = reinterpret_cast<const float4*>(src)[lane + i * 64];
    ushort4 b;
    b.x = f2bf(v.x); b.y = f2bf(v.y); b.z = f2bf(v.z); b.w = f2bf(v.w);
    reinterpret_cast<ushort4*>(dst)[lane + i * 64] = b;
    ss += v.x * v.x + v.y * v.y + v.z * v.z + v.w * v.w;
  }
#pragma unroll
  for (int m = 32; m >= 1; m >>= 1) ss += __shfl_xor(ss, m, 64);
  if (lane == 0) {
    if (isS) smag[row] = rsqrtf(fmaxf(ss, 1e-10f));
    else     partials[row] = ss;
  }
}

// ---------------- GEMM: 256^2 balanced 8-phase ----------------
// Phase layout (per K-tile: 4 phases = quadrants (s0,L)(s0,H)(s1,L)(s1,H)):
//   phase p body: [stage 1 SP pair][VMW(4)][BARRIER][6 ds_reads for p+1]
//                 [setprio1; 16 MFMA on regs loaded at p-1; setprio0]
// Stage slots ph0..7: SP2(1) SP3(1) SP4(1) SP1(0') SP2(0') SP3(0') SP4(0') SP1(1')
// VMW(4) invariant: at phase p, drained through phase p-2's loads; every
// staged region's first reader is >=2 phases after its stage (ledger
// verified per-region); write-after-read gaps all >=2 barriers.
__global__ __launch_bounds__(512, 2) void gemm_bt(
    const unsigned short* __restrict__ A,  // [M, K] bf16 (support)
    const unsigned short* __restrict__ B,  // [N, K] bf16 (input)
    const float* __restrict__ smag,        // [M]
    const float* __restrict__ partials,    // [2048] input-row sumsq partials
    float* __restrict__ C) {               // [M, N]
  __shared__ __align__(16) unsigned short lA[32768];  // 2 buf x 2 half x 8192
  __shared__ __align__(16) unsigned short lB[32768];
  __shared__ float wsum[8];

  const int t = threadIdx.x;     // 0..511
  const int lane = t & 63;
  const int wave = t >> 6;       // 0..7
  const int wr = wave >> 2;      // 0..1  (M half)
  const int wc = wave & 3;       // 0..3  (N quarter)

  // XCD swizzle: 256 blocks, 1/CU. Each XCD: 4 contiguous bm-tiles x 8 bn.
  const int blk = blockIdx.x;
  const int xcd = blk & 7;
  const int slot = blk >> 3;     // 0..31
  const int bm = (xcd * 4 + (slot & 3)) * BM;
  const int bn = (slot >> 2) * BN;

  // Input Frobenius-norm partials reduce; VMW(0) keeps vmcnt queue pure-stage.
  {
    float p = partials[t] + partials[t + 512] + partials[t + 1024] + partials[t + 1536];
#pragma unroll
    for (int m = 32; m >= 1; m >>= 1) p += __shfl_xor(p, m, 64);
    if (lane == 0) wsum[wave] = p;
  }
  asm volatile("s_waitcnt vmcnt(0)" ::: "memory");

  // Staging: thread t -> row-in-load t>>3, stored chunk t&7 holds logical
  // kc = (t&7)^(row&7) (XOR swizzle via pre-swizzled global source).
  const int srow = t >> 3;
  const int skc = (t & 7) ^ (srow & 7);
  const unsigned short* gA[4];   // load j: tile rows [64j, 64j+64)
  const unsigned short* gB[4];
  int aoff[4];
#pragma unroll
  for (int j = 0; j < 4; ++j) {
    gA[j] = A + (size_t)(bm + j * 64 + srow) * K_DIM + skc * 8;
    gB[j] = B + (size_t)(bn + j * 64 + srow) * K_DIM + skc * 8;
    aoff[j] = (j >> 1) * 8192 + (j & 1) * 4096 + wave * 512;
  }

#define STAGE_A(j, buf) do { GLOAD_LDS16(gA[j], &lA[(buf) * 16384 + aoff[j]]); gA[j] += BK; } while (0)
#define STAGE_B(j, buf) do { GLOAD_LDS16(gB[j], &lB[(buf) * 16384 + aoff[j]]); gB[j] += BK; } while (0)
#define SP1(buf) do { STAGE_B(0, buf); STAGE_B(1, buf); } while (0)  // B rows 0-127
#define SP2(buf) do { STAGE_B(2, buf); STAGE_B(3, buf); } while (0)  // B rows 128-255
#define SP3(buf) do { STAGE_A(0, buf); STAGE_A(2, buf); } while (0)  // A mi 0-3 (both halves)
#define SP4(buf) do { STAGE_A(1, buf); STAGE_A(3, buf); } while (0)  // A mi 4-7 (both halves)

  // Fragment read bases (swizzled layout, 0 conflicts verified R1-R3).
  const int fr = lane & 15;
  const int q = lane >> 4;
  const int pc0 = (q ^ (fr & 7)) * 8;        // k-step s=0 chunk offset (shorts)
  const int pc1 = ((4 + q) ^ (fr & 7)) * 8;  // k-step s=1
  const unsigned short* rA = lA + wr * 8192 + fr * 64;
  const unsigned short* rB = lB + (wc >> 1) * 8192 + ((wc & 1) * 64 + fr) * 64;

  short8 afA[4], afB[4];   // A frag banks: L-half / H-half quadrants
  short8 bf0[4], bf1[4];   // B frag banks: s0 / s1
  float4v acc[8][4];
#pragma unroll
  for (int i = 0; i < 8; ++i)
#pragma unroll
    for (int j = 0; j < 4; ++j) acc[i][j] = (float4v)0.0f;

#define BARRIER() __builtin_amdgcn_s_barrier()
#define VMW(n) asm volatile("s_waitcnt vmcnt(" #n ")" ::: "memory")
#define PRIO1() __builtin_amdgcn_s_setprio(1)
#define PRIO0() __builtin_amdgcn_s_setprio(0)

  // LA(bank, buf, half, s): 4 A-frags (mi = half*4 .. +3) at k-step s.
#define LA(bank, buf, half, s) do {                                            \
    _Pragma("unroll") for (int m = 0; m < 4; ++m)                              \
      bank[m] = *reinterpret_cast<const short8*>(                              \
          rA + (buf) * 16384 + ((half) * 4 + m) * 1024 + ((s) ? pc1 : pc0));   \
  } while (0)

  // LB2(bank, buf, s, j0): 2 B-frags (nj = j0, j0+1) at k-step s.
#define LB2(bank, buf, s, j0) do {                                             \
    _Pragma("unroll") for (int n = 0; n < 2; ++n)                              \
      bank[(j0) + n] = *reinterpret_cast<const short8*>(                       \
          rB + (buf) * 16384 + ((j0) + n) * 1024 + ((s) ? pc1 : pc0));         \
  } while (0)

  // MQ(half, abank, bbank): one quadrant = 4mi x 4nj x K=32 -> 16 MFMA.
#define MQ(half, abank, bbank) do {                                            \
    PRIO1();                                                                   \
    _Pragma("unroll") for (int m = 0; m < 4; ++m)                              \
    _Pragma("unroll") for (int n = 0; n < 4; ++n)                              \
      acc[(half) * 4 + m][n] = __builtin_amdgcn_mfma_f32_16x16x32_bf16(        \
          abank[m], bbank[n], acc[(half) * 4 + m][n], 0, 0, 0);                \
    PRIO0();                                                                   \
  } while (0)

  // Prologue: T0 full + T1.B-lo; drain T0; preload ph0 operands.
  SP1(0); SP2(0); SP3(0); SP4(0);   // T0 (10 loads total incl. next line)
  SP1(1);
  VMW(2);                           // T0 landed; SP1(1) in flight
  BARRIER();                        // publishes staging + wsum
  LB2(bf0, 0, 0, 0); LB2(bf0, 0, 0, 2);  // bf a(s0) nj0-3
  LA(afA, 0, 0, 0);                      // af a(s0,L)

#pragma unroll 1
  for (int it = 0; it < NITER - 1; ++it) {
    /*ph0*/ SP2(1); VMW(4); BARRIER(); LA(afB, 0, 1, 0); LB2(bf1, 0, 1, 0); MQ(0, afA, bf0);
    /*ph1*/ SP3(1); VMW(4); BARRIER(); LA(afA, 0, 0, 1); LB2(bf1, 0, 1, 2); MQ(1, afB, bf0);
    /*ph2*/ SP4(1); VMW(4); BARRIER(); LA(afB, 0, 1, 1); LB2(bf0, 1, 0, 0); MQ(0, afA, bf1);
    /*ph3*/ SP1(0); VMW(4); BARRIER(); LA(afA, 1, 0, 0); LB2(bf0, 1, 0, 2); MQ(1, afB, bf1);
    /*ph4*/ SP2(0); VMW(4); BARRIER(); LA(afB, 1, 1, 0); LB2(bf1, 1, 1, 0); MQ(0, afA, bf0);
    /*ph5*/ SP3(0); VMW(4); BARRIER(); LA(afA, 1, 0, 1); LB2(bf1, 1, 1, 2); MQ(1, afB, bf0);
    /*ph6*/ SP4(0); VMW(4); BARRIER(); LA(afB, 1, 1, 1); LB2(bf0, 0, 0, 0); MQ(0, afA, bf1);
    /*ph7*/ SP1(1); VMW(4); BARRIER(); LA(afA, 0, 0, 0); LB2(bf0, 0, 0, 2); MQ(1, afB, bf1);
  }
  // Tail iteration (tile a=T14 buf0, b=T15 buf1): finish T15 staging, no
  // next-iter stages; drains tighten VMW(2)@ph3, VMW(0)@ph4.
  /*ph0*/ SP2(1); VMW(4); BARRIER(); LA(afB, 0, 1, 0); LB2(bf1, 0, 1, 0); MQ(0, afA, bf0);
  /*ph1*/ SP3(1); VMW(4); BARRIER(); LA(afA, 0, 0, 1); LB2(bf1, 0, 1, 2); MQ(1, afB, bf0);
  /*ph2*/ SP4(1); VMW(4); BARRIER(); LA(afB, 0, 1, 1); LB2(bf0, 1, 0, 0); MQ(0, afA, bf1);
  /*ph3*/         VMW(2); BARRIER(); LA(afA, 1, 0, 0); LB2(bf0, 1, 0, 2); MQ(1, afB, bf1);
  /*ph4*/         VMW(0); BARRIER(); LA(afB, 1, 1, 0); LB2(bf1, 1, 1, 0); MQ(0, afA, bf0);
  /*ph5*/                 BARRIER(); LA(afA, 1, 0, 1); LB2(bf1, 1, 1, 2); MQ(1, afB, bf0);
  /*ph6*/                 BARRIER(); LA(afB, 1, 1, 1);                    MQ(0, afA, bf1);
  /*ph7*/                 BARRIER();                                      MQ(1, afB, bf1);

  // Epilogue: C/D layout col = lane&15, row = (lane>>4)*4 + reg.
  // Non-temporal stores: C is never re-read; avoid polluting L2 A/B lines.
  const float imag = rsqrtf(fmaxf(wsum[0] + wsum[1] + wsum[2] + wsum[3] +
                                  wsum[4] + wsum[5] + wsum[6] + wsum[7], 1e-10f));
#pragma unroll
  for (int mi = 0; mi < 8; ++mi) {
    const int rbase = bm + wr * 128 + mi * 16 + q * 4;
#pragma unroll
    for (int r = 0; r < 4; ++r) {
      const int row = rbase + r;
      const float sc = smag[row] * imag;
      float* crow = C + (size_t)row * N_DIM + bn + wc * 64 + fr;
#pragma unroll
      for (int nj = 0; nj < 4; ++nj)
        __builtin_nontemporal_store(acc[mi][nj][r] * sc, crow + nj * 16);
    }
  }
}

// ---------------- launch ----------------
extern "C" void kernel_launch(void* const* d_in, const int* in_sizes, int n_in,
                              void* d_out, int out_size, void* d_ws, size_t ws_size,
                              hipStream_t stream) {
  const float* S = (const float*)d_in[0];  // support_set [8192,1024]
  const float* I = (const float*)d_in[1];  // input_image [2048,1024]
  float* out = (float*)d_out;

  // ws layout: Sb bf16 16MB | Ib bf16 4MB | smag 32KB | partials 8KB
  unsigned char* ws = (unsigned char*)d_ws;
  unsigned short* Sb = (unsigned short*)ws;
  unsigned short* Ib = (unsigned short*)(ws + (size_t)M_DIM * K_DIM * 2);
  float* smag = (float*)(ws + (size_t)M_DIM * K_DIM * 2 + (size_t)N_DIM * K_DIM * 2);
  float* partials = smag + M_DIM;

  hipLaunchKernelGGL(prep, dim3(2560), dim3(256), 0, stream,
                     S, I, Sb, Ib, smag, partials);
  hipLaunchKernelGGL(gemm_bt, dim3((M_DIM / BM) * (N_DIM / BN)), dim3(512), 0, stream,
                     Sb, Ib, smag, partials, out);
}

// Round 5
// 129.482 us; speedup vs baseline: 1.0489x; 1.0489x over previous
//
#include <hip/hip_runtime.h>
#include <hip/hip_bf16.h>
#include <stdint.h>
#include <stddef.h>

// DistanceNetwork: sims[n,b] = dot(support[n], input[b]) * rsqrt(||support[n]||^2) * rsqrt(||input||_F^2)
//   support_set: [8192, 1024] fp32   input_image: [2048, 1024] fp32   out: [8192, 2048] fp32
#define M_DIM 8192
#define N_DIM 2048
#define K_DIM 1024

// R5: 256x256, 8-phase. vs R3/R4:
//  - sched_group_barrier pin per phase: DS_READ x6 THEN MFMA x16. R3's
//    counters showed 1162 cyc/phase = 576 (LDS) + 621 (MFMA) serial: the
//    compiler sinks the independent prefetch reads to their use point.
//    SGB forces issue-ahead so LDS hides under MFMA.
//  - balanced 6 reads/phase (R4's quadrant map) BUT stage slots re-derived
//    for min stage->first-read gap of 3 phases -> uniform VMW(6) draining
//    3-phase-old (~1900cyc) loads. (R4's gap-2/VMW(4) stalled every phase.)
//  - regular C stores (R4's nontemporal added +12.6MB HBM writes).
#define BM 256
#define BN 256
#define BK 64
#define NKT (K_DIM / BK)  // 16 K-tiles
#define NITER (NKT / 2)   // 8 iterations (7 full + 1 tail)

typedef __attribute__((ext_vector_type(8))) short short8;   // 8 bf16 = 4 VGPRs
typedef __attribute__((ext_vector_type(4))) float float4v;  // MFMA C/D

// fp32 -> bf16 RNE
static __device__ __forceinline__ unsigned short f2bf(float x) {
  union { float f; unsigned u; } c; c.f = x;
  return (unsigned short)((c.u + 0x7FFFu + ((c.u >> 16) & 1u)) >> 16);
}

#define GLOAD_LDS16(g, l)                                           \
  __builtin_amdgcn_global_load_lds(                                 \
      (const __attribute__((address_space(1))) void*)(g),           \
      (__attribute__((address_space(3))) void*)(l), 16, 0, 0)

// ---------------- fused prep ----------------
// wave-per-row. Blocks [0,2048): support rows 4*blk+wave -> Sb + smag.
// Blocks [2048,2560): input rows -> Ib + partials.
__global__ __launch_bounds__(256) void prep(
    const float* __restrict__ S, const float* __restrict__ I,
    unsigned short* __restrict__ Sb, unsigned short* __restrict__ Ib,
    float* __restrict__ smag, float* __restrict__ partials) {
  const int t = threadIdx.x;
  const int lane = t & 63;
  const int wave = t >> 6;
  const int blk = blockIdx.x;
  const bool isS = blk < 2048;
  const int row = (isS ? blk : blk - 2048) * 4 + wave;
  const float* src = (isS ? S : I) + (size_t)row * K_DIM;
  unsigned short* dst = (isS ? Sb : Ib) + (size_t)row * K_DIM;

  float ss = 0.f;
#pragma unroll
  for (int i = 0; i < 4; ++i) {
    const float4 v = reinterpret_cast<const float4*>(src)[lane + i * 64];
    ushort4 b;
    b.x = f2bf(v.x); b.y = f2bf(v.y); b.z = f2bf(v.z); b.w = f2bf(v.w);
    reinterpret_cast<ushort4*>(dst)[lane + i * 64] = b;
    ss += v.x * v.x + v.y * v.y + v.z * v.z + v.w * v.w;
  }
#pragma unroll
  for (int m = 32; m >= 1; m >>= 1) ss += __shfl_xor(ss, m, 64);
  if (lane == 0) {
    if (isS) smag[row] = rsqrtf(fmaxf(ss, 1e-10f));
    else     partials[row] = ss;
  }
}

// ---------------- GEMM: 256^2 SGB-pinned balanced 8-phase ----------------
// Phase p body: [stage 1 SP][VMW(6)][BARRIER][SGB: DS_READ x6, MFMA x16]
//               [6 ds_reads for p+1][setprio1; 16 MFMA on p-1 regs; setprio0]
// Stage slots ph0..7: SP3(1) SP4(1) SP1(0') SP2(0') SP3(0') SP4(0') SP1(1') SP2(1')
// Read slots  ph0..7 (prefetch for next phase's MFMA):
//   ph0: A-hi b0 s0 + B b0 s1 nj01     ph1: A-lo b0 s1 + B b0 s1 nj23
//   ph2: A-hi b0 s1 + B b1 s0 nj01     ph3: A-lo b1 s0 + B b1 s0 nj23
//   ph4: A-hi b1 s0 + B b1 s1 nj01     ph5: A-lo b1 s1 + B b1 s1 nj23
//   ph6: A-hi b1 s1 + B b0' s0 nj01    ph7: A-lo b0' s0 + B b0' s0 nj23
// Ledger (VMW(6) invariant: entering p, in flight = SPs of p-3..p-1; drain
// at p retires SP(p-3)): every read at p targets regions staged <= p-3 ✓;
// drained loads are >=3 phases (~1900cyc) old ✓; write-after-read: every
// restaged region's last ds_read issued >=1 phase before the stage ✓.
__global__ __launch_bounds__(512, 2) void gemm_bt(
    const unsigned short* __restrict__ A,  // [M, K] bf16 (support)
    const unsigned short* __restrict__ B,  // [N, K] bf16 (input)
    const float* __restrict__ smag,        // [M]
    const float* __restrict__ partials,    // [2048] input-row sumsq partials
    float* __restrict__ C) {               // [M, N]
  __shared__ __align__(16) unsigned short lA[32768];  // 2 buf x 2 half x 8192
  __shared__ __align__(16) unsigned short lB[32768];
  __shared__ float wsum[8];

  const int t = threadIdx.x;     // 0..511
  const int lane = t & 63;
  const int wave = t >> 6;       // 0..7
  const int wr = wave >> 2;      // 0..1  (M half)
  const int wc = wave & 3;       // 0..3  (N quarter)

  // XCD swizzle: 256 blocks, 1/CU. Each XCD: 4 contiguous bm-tiles x 8 bn.
  const int blk = blockIdx.x;
  const int xcd = blk & 7;
  const int slot = blk >> 3;     // 0..31
  const int bm = (xcd * 4 + (slot & 3)) * BM;
  const int bn = (slot >> 2) * BN;

  // Input Frobenius-norm partials reduce; VMW(0) keeps vmcnt queue pure-stage.
  {
    float p = partials[t] + partials[t + 512] + partials[t + 1024] + partials[t + 1536];
#pragma unroll
    for (int m = 32; m >= 1; m >>= 1) p += __shfl_xor(p, m, 64);
    if (lane == 0) wsum[wave] = p;
  }
  asm volatile("s_waitcnt vmcnt(0)" ::: "memory");

  // Staging: thread t -> row-in-load t>>3, stored chunk t&7 holds logical
  // kc = (t&7)^(row&7) (XOR swizzle via pre-swizzled global source).
  const int srow = t >> 3;
  const int skc = (t & 7) ^ (srow & 7);
  const unsigned short* gA[4];   // load j: tile rows [64j, 64j+64)
  const unsigned short* gB[4];
  int aoff[4];
#pragma unroll
  for (int j = 0; j < 4; ++j) {
    gA[j] = A + (size_t)(bm + j * 64 + srow) * K_DIM + skc * 8;
    gB[j] = B + (size_t)(bn + j * 64 + srow) * K_DIM + skc * 8;
    aoff[j] = (j >> 1) * 8192 + (j & 1) * 4096 + wave * 512;
  }

#define STAGE_A(j, buf) do { GLOAD_LDS16(gA[j], &lA[(buf) * 16384 + aoff[j]]); gA[j] += BK; } while (0)
#define STAGE_B(j, buf) do { GLOAD_LDS16(gB[j], &lB[(buf) * 16384 + aoff[j]]); gB[j] += BK; } while (0)
#define SP1(buf) do { STAGE_B(0, buf); STAGE_B(1, buf); } while (0)  // B rows 0-127
#define SP2(buf) do { STAGE_B(2, buf); STAGE_B(3, buf); } while (0)  // B rows 128-255
#define SP3(buf) do { STAGE_A(0, buf); STAGE_A(2, buf); } while (0)  // A mi 0-3 (both halves)
#define SP4(buf) do { STAGE_A(1, buf); STAGE_A(3, buf); } while (0)  // A mi 4-7 (both halves)

  // Fragment read bases (swizzled layout, 0 conflicts verified R1-R4).
  const int fr = lane & 15;
  const int q = lane >> 4;
  const int pc0 = (q ^ (fr & 7)) * 8;        // k-step s=0 chunk offset (shorts)
  const int pc1 = ((4 + q) ^ (fr & 7)) * 8;  // k-step s=1
  const unsigned short* rA = lA + wr * 8192 + fr * 64;
  const unsigned short* rB = lB + (wc >> 1) * 8192 + ((wc & 1) * 64 + fr) * 64;

  short8 afA[4], afB[4];   // A frag banks: L-half / H-half quadrants
  short8 bf0[4], bf1[4];   // B frag banks: s0 / s1
  float4v acc[8][4];
#pragma unroll
  for (int i = 0; i < 8; ++i)
#pragma unroll
    for (int j = 0; j < 4; ++j) acc[i][j] = (float4v)0.0f;

#define BARRIER() __builtin_amdgcn_s_barrier()
#define VMW(n) asm volatile("s_waitcnt vmcnt(" #n ")" ::: "memory")
#define PRIO1() __builtin_amdgcn_s_setprio(1)
#define PRIO0() __builtin_amdgcn_s_setprio(0)
// Pin: emit 6 ds_reads first, then the 16-MFMA cluster (T19; LLVM
// SchedGroupMask DS_READ=0x100, MFMA=0x8).
#define SGB6() do {                                                            \
    __builtin_amdgcn_sched_group_barrier(0x100, 6, 0);                         \
    __builtin_amdgcn_sched_group_barrier(0x008, 16, 0);                        \
  } while (0)
#define SGB4() do {                                                            \
    __builtin_amdgcn_sched_group_barrier(0x100, 4, 0);                         \
    __builtin_amdgcn_sched_group_barrier(0x008, 16, 0);                        \
  } while (0)

  // LA(bank, buf, half, s): 4 A-frags (mi = half*4 .. +3) at k-step s.
#define LA(bank, buf, half, s) do {                                            \
    _Pragma("unroll") for (int m = 0; m < 4; ++m)                              \
      bank[m] = *reinterpret_cast<const short8*>(                              \
          rA + (buf) * 16384 + ((half) * 4 + m) * 1024 + ((s) ? pc1 : pc0));   \
  } while (0)

  // LB2(bank, buf, s, j0): 2 B-frags (nj = j0, j0+1) at k-step s.
#define LB2(bank, buf, s, j0) do {                                             \
    _Pragma("unroll") for (int n = 0; n < 2; ++n)                              \
      bank[(j0) + n] = *reinterpret_cast<const short8*>(                       \
          rB + (buf) * 16384 + ((j0) + n) * 1024 + ((s) ? pc1 : pc0));         \
  } while (0)

  // MQ(half, abank, bbank): one quadrant = 4mi x 4nj x K=32 -> 16 MFMA.
#define MQ(half, abank, bbank) do {                                            \
    PRIO1();                                                                   \
    _Pragma("unroll") for (int m = 0; m < 4; ++m)                              \
    _Pragma("unroll") for (int n = 0; n < 4; ++n)                              \
      acc[(half) * 4 + m][n] = __builtin_amdgcn_mfma_f32_16x16x32_bf16(        \
          abank[m], bbank[n], acc[(half) * 4 + m][n], 0, 0, 0);                \
    PRIO0();                                                                   \
  } while (0)

  // Prologue: stage T0 complete + T1.B (6 SPs, in steady queue order);
  // VMW(6) retires SP1(0),SP2(0),SP3(0) -> remaining {SP4(0),SP1(1),SP2(1)}
  // == the steady-state entering-ph0 invariant {p-3,p-2,p-1}.
  SP1(0); SP2(0); SP3(0); SP4(0);
  SP1(1); SP2(1);
  VMW(6);
  BARRIER();                              // publishes staging + wsum
  LB2(bf0, 0, 0, 0); LB2(bf0, 0, 0, 2);   // B b0 s0 nj0-3
  LA(afA, 0, 0, 0);                       // A-lo b0 s0

#pragma unroll 1
  for (int it = 0; it < NITER - 1; ++it) {
    /*ph0*/ SP3(1); VMW(6); BARRIER(); SGB6(); LA(afB, 0, 1, 0); LB2(bf1, 0, 1, 0); MQ(0, afA, bf0);
    /*ph1*/ SP4(1); VMW(6); BARRIER(); SGB6(); LA(afA, 0, 0, 1); LB2(bf1, 0, 1, 2); MQ(1, afB, bf0);
    /*ph2*/ SP1(0); VMW(6); BARRIER(); SGB6(); LA(afB, 0, 1, 1); LB2(bf0, 1, 0, 0); MQ(0, afA, bf1);
    /*ph3*/ SP2(0); VMW(6); BARRIER(); SGB6(); LA(afA, 1, 0, 0); LB2(bf0, 1, 0, 2); MQ(1, afB, bf1);
    /*ph4*/ SP3(0); VMW(6); BARRIER(); SGB6(); LA(afB, 1, 1, 0); LB2(bf1, 1, 1, 0); MQ(0, afA, bf0);
    /*ph5*/ SP4(0); VMW(6); BARRIER(); SGB6(); LA(afA, 1, 0, 1); LB2(bf1, 1, 1, 2); MQ(1, afB, bf0);
    /*ph6*/ SP1(1); VMW(6); BARRIER(); SGB6(); LA(afB, 1, 1, 1); LB2(bf0, 0, 0, 0); MQ(0, afA, bf1);
    /*ph7*/ SP2(1); VMW(6); BARRIER(); SGB6(); LA(afA, 0, 0, 0); LB2(bf0, 0, 0, 2); MQ(1, afB, bf1);
  }
  // Tail iteration (T14 in buf0, T15 in buf1): stage only T15.A (ph0/ph1);
  // drains tighten VMW(6)->(4)->(2)->(0); skip next-iter prefetch reads.
  /*ph0*/ SP3(1); VMW(6); BARRIER(); SGB6(); LA(afB, 0, 1, 0); LB2(bf1, 0, 1, 0); MQ(0, afA, bf0);
  /*ph1*/ SP4(1);         BARRIER(); SGB6(); LA(afA, 0, 0, 1); LB2(bf1, 0, 1, 2); MQ(1, afB, bf0);
  /*ph2*/         VMW(4); BARRIER(); SGB6(); LA(afB, 0, 1, 1); LB2(bf0, 1, 0, 0); MQ(0, afA, bf1);
  /*ph3*/         VMW(2); BARRIER(); SGB6(); LA(afA, 1, 0, 0); LB2(bf0, 1, 0, 2); MQ(1, afB, bf1);
  /*ph4*/         VMW(0); BARRIER(); SGB6(); LA(afB, 1, 1, 0); LB2(bf1, 1, 1, 0); MQ(0, afA, bf0);
  /*ph5*/                 BARRIER(); SGB6(); LA(afA, 1, 0, 1); LB2(bf1, 1, 1, 2); MQ(1, afB, bf0);
  /*ph6*/                 BARRIER(); SGB4(); LA(afB, 1, 1, 1);                    MQ(0, afA, bf1);
  /*ph7*/                 BARRIER();                                              MQ(1, afB, bf1);

  // Epilogue: C/D layout col = lane&15, row = (lane>>4)*4 + reg.
  // Regular stores (R4's nontemporal stores added +12.6MB HBM writes).
  const float imag = rsqrtf(fmaxf(wsum[0] + wsum[1] + wsum[2] + wsum[3] +
                                  wsum[4] + wsum[5] + wsum[6] + wsum[7], 1e-10f));
#pragma unroll
  for (int mi = 0; mi < 8; ++mi) {
    const int rbase = bm + wr * 128 + mi * 16 + q * 4;
#pragma unroll
    for (int r = 0; r < 4; ++r) {
      const int row = rbase + r;
      const float sc = smag[row] * imag;
      float* crow = C + (size_t)row * N_DIM + bn + wc * 64 + fr;
#pragma unroll
      for (int nj = 0; nj < 4; ++nj) crow[nj * 16] = acc[mi][nj][r] * sc;
    }
  }
}

// ---------------- launch ----------------
extern "C" void kernel_launch(void* const* d_in, const int* in_sizes, int n_in,
                              void* d_out, int out_size, void* d_ws, size_t ws_size,
                              hipStream_t stream) {
  const float* S = (const float*)d_in[0];  // support_set [8192,1024]
  const float* I = (const float*)d_in[1];  // input_image [2048,1024]
  float* out = (float*)d_out;

  // ws layout: Sb bf16 16MB | Ib bf16 4MB | smag 32KB | partials 8KB
  unsigned char* ws = (unsigned char*)d_ws;
  unsigned short* Sb = (unsigned short*)ws;
  unsigned short* Ib = (unsigned short*)(ws + (size_t)M_DIM * K_DIM * 2);
  float* smag = (float*)(ws + (size_t)M_DIM * K_DIM * 2 + (size_t)N_DIM * K_DIM * 2);
  float* partials = smag + M_DIM;

  hipLaunchKernelGGL(prep, dim3(2560), dim3(256), 0, stream,
                     S, I, Sb, Ib, smag, partials);
  hipLaunchKernelGGL(gemm_bt, dim3((M_DIM / BM) * (N_DIM / BN)), dim3(512), 0, stream,
                     Sb, Ib, smag, partials, out);
}

// Round 6
// 126.677 us; speedup vs baseline: 1.0721x; 1.0221x over previous
//
#include <hip/hip_runtime.h>
#include <hip/hip_bf16.h>
#include <stdint.h>
#include <stddef.h>

// DistanceNetwork: sims[n,b] = dot(support[n], input[b]) * rsqrt(||support[n]||^2) * rsqrt(||input||_F^2)
//   support_set: [8192, 1024] fp32   input_image: [2048, 1024] fp32   out: [8192, 2048] fp32
#define M_DIM 8192
#define N_DIM 2048
#define K_DIM 1024

// R6 = R3 (measured best, 42.8us) + two surgical fixes:
//  (1) LOADB 8-read bursts split 4+4 across adjacent phases (peak phase
//      LDS 1150 -> 768 cyc). VMW schedule UNCHANGED from R3.
//  (2) sched_group_barrier per phase (DS_READ x n, then MFMA x16): R3's
//      measured 9300 cyc/iter == exact serial sum of reads+MFMA; SGB forces
//      reads to issue ahead so LDS hides under the MFMA cluster.
// (R4/R5's balanced-map + per-phase-VMW rewrite regressed to 53us — reverted.)
#define BM 256
#define BN 256
#define BK 64
#define NKT (K_DIM / BK)  // 16 K-tiles
#define NITER (NKT / 2)   // 8 iterations (7 full + 1 tail)

typedef __attribute__((ext_vector_type(8))) short short8;   // 8 bf16 = 4 VGPRs
typedef __attribute__((ext_vector_type(4))) float float4v;  // MFMA C/D

// fp32 -> bf16 RNE
static __device__ __forceinline__ unsigned short f2bf(float x) {
  union { float f; unsigned u; } c; c.f = x;
  return (unsigned short)((c.u + 0x7FFFu + ((c.u >> 16) & 1u)) >> 16);
}

#define GLOAD_LDS16(g, l)                                           \
  __builtin_amdgcn_global_load_lds(                                 \
      (const __attribute__((address_space(1))) void*)(g),           \
      (__attribute__((address_space(3))) void*)(l), 16, 0, 0)

// ---------------- fused prep ----------------
// wave-per-row. Blocks [0,2048): support rows 4*blk+wave -> Sb + smag.
// Blocks [2048,2560): input rows -> Ib + partials.
__global__ __launch_bounds__(256) void prep(
    const float* __restrict__ S, const float* __restrict__ I,
    unsigned short* __restrict__ Sb, unsigned short* __restrict__ Ib,
    float* __restrict__ smag, float* __restrict__ partials) {
  const int t = threadIdx.x;
  const int lane = t & 63;
  const int wave = t >> 6;
  const int blk = blockIdx.x;
  const bool isS = blk < 2048;
  const int row = (isS ? blk : blk - 2048) * 4 + wave;
  const float* src = (isS ? S : I) + (size_t)row * K_DIM;
  unsigned short* dst = (isS ? Sb : Ib) + (size_t)row * K_DIM;

  float ss = 0.f;
#pragma unroll
  for (int i = 0; i < 4; ++i) {
    const float4 v = reinterpret_cast<const float4*>(src)[lane + i * 64];
    ushort4 b;
    b.x = f2bf(v.x); b.y = f2bf(v.y); b.z = f2bf(v.z); b.w = f2bf(v.w);
    reinterpret_cast<ushort4*>(dst)[lane + i * 64] = b;
    ss += v.x * v.x + v.y * v.y + v.z * v.z + v.w * v.w;
  }
#pragma unroll
  for (int m = 32; m >= 1; m >>= 1) ss += __shfl_xor(ss, m, 64);
  if (lane == 0) {
    if (isS) smag[row] = rsqrtf(fmaxf(ss, 1e-10f));
    else     partials[row] = ss;
  }
}

// ---------------- GEMM: 256^2 prefetch-pipelined 8-phase (R3 sched) ----------------
// Phase p: [stage SP][counted VMW (R3 placement)][BARRIER][SGB pin]
//          [ds_reads for p+1 (4 or 8)][setprio1; 16 MFMA on p-1 regs; setprio0]
// vmcnt ledger identical to R3 (verified there, passed):
//   ph2: VMW(10), ph4: VMW(8), ph6: VMW(10), ph8: VMW(8).
// B-frag loads per K-tile split: LO (nj0,1) in the VMW(8) phase (regions just
// drained), HI (nj2,3) in the following phase (same regions, still landed);
// HI's consumer is its own phase's MFMA -> lgkm-covered, ~200cyc exposure.
__global__ __launch_bounds__(512, 2) void gemm_bt(
    const unsigned short* __restrict__ A,  // [M, K] bf16 (support)
    const unsigned short* __restrict__ B,  // [N, K] bf16 (input)
    const float* __restrict__ smag,        // [M]
    const float* __restrict__ partials,    // [2048] input-row sumsq partials
    float* __restrict__ C) {               // [M, N]
  __shared__ __align__(16) unsigned short lA[32768];  // 2 buf x 2 half x 8192
  __shared__ __align__(16) unsigned short lB[32768];
  __shared__ float wsum[8];

  const int t = threadIdx.x;     // 0..511
  const int lane = t & 63;
  const int wave = t >> 6;       // 0..7
  const int wr = wave >> 2;      // 0..1  (M half)
  const int wc = wave & 3;       // 0..3  (N quarter)

  // XCD swizzle: 256 blocks, 1/CU. Each XCD: 4 contiguous bm-tiles x 8 bn.
  const int blk = blockIdx.x;
  const int xcd = blk & 7;
  const int slot = blk >> 3;     // 0..31
  const int bm = (xcd * 4 + (slot & 3)) * BM;
  const int bn = (slot >> 2) * BN;

  // Input Frobenius-norm partials reduce. VMW(0) keeps vmcnt queue pure-stage.
  {
    float p = partials[t] + partials[t + 512] + partials[t + 1024] + partials[t + 1536];
#pragma unroll
    for (int m = 32; m >= 1; m >>= 1) p += __shfl_xor(p, m, 64);
    if (lane == 0) wsum[wave] = p;
  }
  asm volatile("s_waitcnt vmcnt(0)" ::: "memory");

  // Staging: thread t covers row-in-load = t>>3; stored chunk t&7 holds
  // logical kc = (t&7)^(row&7)  (XOR swizzle via pre-swizzled global src).
  const int srow = t >> 3;
  const int skc = (t & 7) ^ (srow & 7);
  const unsigned short* gA[4];   // loads j: tile rows [64j, 64j+64)
  const unsigned short* gB[4];
  int aoff[4];                   // LDS wave-uniform dest (shorts), per load j
#pragma unroll
  for (int j = 0; j < 4; ++j) {
    gA[j] = A + (size_t)(bm + j * 64 + srow) * K_DIM + skc * 8;
    gB[j] = B + (size_t)(bn + j * 64 + srow) * K_DIM + skc * 8;
    aoff[j] = (j >> 1) * 8192 + (j & 1) * 4096 + wave * 512;
  }

#define STAGE_A(j, buf) do { GLOAD_LDS16(gA[j], &lA[(buf) * 16384 + aoff[j]]); gA[j] += BK; } while (0)
#define STAGE_B(j, buf) do { GLOAD_LDS16(gB[j], &lB[(buf) * 16384 + aoff[j]]); gB[j] += BK; } while (0)
#define SP1(buf) do { STAGE_B(0, buf); STAGE_B(1, buf); } while (0)  // B rows 0-127
#define SP2(buf) do { STAGE_B(2, buf); STAGE_B(3, buf); } while (0)  // B rows 128-255
#define SP3(buf) do { STAGE_A(0, buf); STAGE_A(2, buf); } while (0)  // A mi 0-3 (both halves)
#define SP4(buf) do { STAGE_A(1, buf); STAGE_A(3, buf); } while (0)  // A mi 4-7 (both halves)

  // Fragment read bases (swizzled layout, 0 conflicts verified R1-R5).
  const int fr = lane & 15;
  const int q = lane >> 4;
  const int pc0 = (q ^ (fr & 7)) * 8;        // k-step s=0 chunk offset (shorts)
  const int pc1 = ((4 + q) ^ (fr & 7)) * 8;  // k-step s=1
  const unsigned short* rA = lA + wr * 8192 + fr * 64;
  const unsigned short* rB = lB + (wc >> 1) * 8192 + ((wc & 1) * 64 + fr) * 64;

  short8 af0[2][2], af1[2][2];   // A frag banks: [m2][s]; odd phases use af0
  short8 bfA[4][2], bfB[4][2];   // B frags per K-tile: [nj][s]
  float4v acc[8][4];
#pragma unroll
  for (int i = 0; i < 8; ++i)
#pragma unroll
    for (int j = 0; j < 4; ++j) acc[i][j] = (float4v)0.0f;

#define BARRIER() __builtin_amdgcn_s_barrier()
#define VMW(n) asm volatile("s_waitcnt vmcnt(" #n ")" ::: "memory")
#define PRIO1() __builtin_amdgcn_s_setprio(1)
#define PRIO0() __builtin_amdgcn_s_setprio(0)
// T19 pin: emit n ds_reads first, then the 16-MFMA cluster.
// LLVM SchedGroupMask: DS_READ=0x100, MFMA=0x8.
#define SGB(n) do {                                                            \
    __builtin_amdgcn_sched_group_barrier(0x100, n, 0);                         \
    __builtin_amdgcn_sched_group_barrier(0x008, 16, 0);                        \
  } while (0)

#define LOADB_LO(bank, buf) do {                                               \
    _Pragma("unroll") for (int nj = 0; nj < 2; ++nj) {                         \
      bank[nj][0] = *reinterpret_cast<const short8*>(rB + (buf) * 16384 + nj * 1024 + pc0); \
      bank[nj][1] = *reinterpret_cast<const short8*>(rB + (buf) * 16384 + nj * 1024 + pc1); \
    } } while (0)

#define LOADB_HI(bank, buf) do {                                               \
    _Pragma("unroll") for (int nj = 2; nj < 4; ++nj) {                         \
      bank[nj][0] = *reinterpret_cast<const short8*>(rB + (buf) * 16384 + nj * 1024 + pc0); \
      bank[nj][1] = *reinterpret_cast<const short8*>(rB + (buf) * 16384 + nj * 1024 + pc1); \
    } } while (0)

#define LOADA(bank, buf, pi) do {                                              \
    _Pragma("unroll") for (int m2 = 0; m2 < 2; ++m2) {                         \
      bank[m2][0] = *reinterpret_cast<const short8*>(rA + (buf) * 16384 + ((pi) * 2 + m2) * 1024 + pc0); \
      bank[m2][1] = *reinterpret_cast<const short8*>(rA + (buf) * 16384 + ((pi) * 2 + m2) * 1024 + pc1); \
    } } while (0)

#define MFMA16(pi, abank, bbank) do {                                          \
    PRIO1();                                                                   \
    _Pragma("unroll") for (int m2 = 0; m2 < 2; ++m2)                           \
    _Pragma("unroll") for (int nj = 0; nj < 4; ++nj) {                         \
      acc[(pi) * 2 + m2][nj] = __builtin_amdgcn_mfma_f32_16x16x32_bf16(        \
          abank[m2][0], bbank[nj][0], acc[(pi) * 2 + m2][nj], 0, 0, 0);        \
      acc[(pi) * 2 + m2][nj] = __builtin_amdgcn_mfma_f32_16x16x32_bf16(        \
          abank[m2][1], bbank[nj][1], acc[(pi) * 2 + m2][nj], 0, 0, 0);        \
    } } while (0)

  // Full iteration (2 K-tiles: buf0 phases 1-4, buf1 phases 5-8).
  // Reads/phase: ph1:8 ph2:4 ph3:4 ph4:8 ph5:8 ph6:4 ph7:4 ph8:8.
#define ITER_F() do {                                                          \
    /* ph1 */ SP4(1);           BARRIER(); SGB(8);                             \
              LOADA(af1, 0, 1); LOADB_HI(bfA, 0); MFMA16(0, af0, bfA);         \
    /* ph2 */ SP1(0); VMW(10);  BARRIER(); SGB(4);                             \
              LOADA(af0, 0, 2); MFMA16(1, af1, bfA);                           \
    /* ph3 */ SP2(0);           BARRIER(); SGB(4);                             \
              LOADA(af1, 0, 3); MFMA16(2, af0, bfA);                           \
    /* ph4 */ SP3(0); VMW(8);   BARRIER(); SGB(8);                             \
              LOADB_LO(bfB, 1); LOADA(af0, 1, 0); MFMA16(3, af1, bfA);         \
    /* ph5 */ SP4(0);           BARRIER(); SGB(8);                             \
              LOADA(af1, 1, 1); LOADB_HI(bfB, 1); MFMA16(0, af0, bfB);         \
    /* ph6 */ SP1(1); VMW(10);  BARRIER(); SGB(4);                             \
              LOADA(af0, 1, 2); MFMA16(1, af1, bfB);                           \
    /* ph7 */ SP2(1);           BARRIER(); SGB(4);                             \
              LOADA(af1, 1, 3); MFMA16(2, af0, bfB);                           \
    /* ph8 */ SP3(1); VMW(8);   BARRIER(); SGB(8);                             \
              LOADB_LO(bfA, 0); LOADA(af0, 0, 0); MFMA16(3, af1, bfB);         \
  } while (0)

  // Tail iteration (T14 buf0, T15 buf1): no next-iter stages; R3 tail drains
  // VMW(8)@ph2, VMW(2)@ph4, VMW(0)@ph6.
#define ITER_T() do {                                                          \
    /* ph1 */ SP4(1);           BARRIER(); SGB(8);                             \
              LOADA(af1, 0, 1); LOADB_HI(bfA, 0); MFMA16(0, af0, bfA);         \
    /* ph2 */ VMW(8);           BARRIER(); SGB(4);                             \
              LOADA(af0, 0, 2); MFMA16(1, af1, bfA);                           \
    /* ph3 */                   BARRIER(); SGB(4);                             \
              LOADA(af1, 0, 3); MFMA16(2, af0, bfA);                           \
    /* ph4 */ VMW(2);           BARRIER(); SGB(8);                             \
              LOADB_LO(bfB, 1); LOADA(af0, 1, 0); MFMA16(3, af1, bfA);         \
    /* ph5 */                   BARRIER(); SGB(8);                             \
              LOADA(af1, 1, 1); LOADB_HI(bfB, 1); MFMA16(0, af0, bfB);         \
    /* ph6 */ VMW(0);           BARRIER(); SGB(4);                             \
              LOADA(af0, 1, 2); MFMA16(1, af1, bfB);                           \
    /* ph7 */                   BARRIER(); SGB(4);                             \
              LOADA(af1, 1, 3); MFMA16(2, af0, bfB);                           \
    /* ph8 */                   BARRIER();                                     \
              MFMA16(3, af1, bfB);                                             \
  } while (0)

  // Prologue (R3): stage T0 fully + T1.{B,A-lo} (14 loads); VMW(6) drains T0;
  // barrier publishes staging + wsum; preload ph1 operands (full bfA).
  SP1(0); SP2(0); SP3(0); SP4(0);   // T0 complete
  SP1(1); SP2(1); SP3(1);           // T1 minus A-hi
  VMW(6);                           // T0 drained; [S1,S2,S3](T1) in flight
  BARRIER();
  LOADB_LO(bfA, 0); LOADB_HI(bfA, 0); LOADA(af0, 0, 0);  // ph1 operands

#pragma unroll 1
  for (int it = 0; it < NITER - 1; ++it) ITER_F();
  ITER_T();

  // Epilogue: C/D layout col = lane&15, row = (lane>>4)*4 + reg
  const float imag = rsqrtf(fmaxf(wsum[0] + wsum[1] + wsum[2] + wsum[3] +
                                  wsum[4] + wsum[5] + wsum[6] + wsum[7], 1e-10f));
#pragma unroll
  for (int mi = 0; mi < 8; ++mi) {
    const int rbase = bm + wr * 128 + mi * 16 + q * 4;
#pragma unroll
    for (int r = 0; r < 4; ++r) {
      const int row = rbase + r;
      const float sc = smag[row] * imag;
      float* crow = C + (size_t)row * N_DIM + bn + wc * 64 + fr;
#pragma unroll
      for (int nj = 0; nj < 4; ++nj) crow[nj * 16] = acc[mi][nj][r] * sc;
    }
  }
}

// ---------------- launch ----------------
extern "C" void kernel_launch(void* const* d_in, const int* in_sizes, int n_in,
                              void* d_out, int out_size, void* d_ws, size_t ws_size,
                              hipStream_t stream) {
  const float* S = (const float*)d_in[0];  // support_set [8192,1024]
  const float* I = (const float*)d_in[1];  // input_image [2048,1024]
  float* out = (float*)d_out;

  // ws layout: Sb bf16 16MB | Ib bf16 4MB | smag 32KB | partials 8KB
  unsigned char* ws = (unsigned char*)d_ws;
  unsigned short* Sb = (unsigned short*)ws;
  unsigned short* Ib = (unsigned short*)(ws + (size_t)M_DIM * K_DIM * 2);
  float* smag = (float*)(ws + (size_t)M_DIM * K_DIM * 2 + (size_t)N_DIM * K_DIM * 2);
  float* partials = smag + M_DIM;

  hipLaunchKernelGGL(prep, dim3(2560), dim3(256), 0, stream,
                     S, I, Sb, Ib, smag, partials);
  hipLaunchKernelGGL(gemm_bt, dim3((M_DIM / BM) * (N_DIM / BN)), dim3(512), 0, stream,
                     Sb, Ib, smag, partials, out);
}

// Round 8
// 124.318 us; speedup vs baseline: 1.0924x; 1.0190x over previous
//
#include <hip/hip_runtime.h>
#include <hip/hip_bf16.h>
#include <stdint.h>
#include <stddef.h>

// DistanceNetwork: sims[n,b] = dot(support[n], input[b]) * rsqrt(||support[n]||^2) * rsqrt(||input||_F^2)
//   support_set: [8192, 1024] fp32   input_image: [2048, 1024] fp32   out: [8192, 2048] fp32
#define M_DIM 8192
#define N_DIM 2048
#define K_DIM 1024

// R8 = R7 resubmitted verbatim (infra failed; never measured).
// R7 = R6 gemm (byte-identical; ~42.3us, best measured) + prep-v2 only.
// prep-v2: max-width memory ops — 4x16B loads + 2x16B stores per lane
// (was 4x16B loads + 4x8B ushort4 stores). Single-variable round to
// disambiguate the time budget: totals never added up (2 fills 85us +
// gemm 42.4 + prep>=10 > 126.7 measured); prep is the only large
// unmeasured controllable (never in top-5, could be 12..42us).
#define BM 256
#define BN 256
#define BK 64
#define NKT (K_DIM / BK)  // 16 K-tiles
#define NITER (NKT / 2)   // 8 iterations (7 full + 1 tail)

typedef __attribute__((ext_vector_type(8))) short short8;   // 8 bf16 = 4 VGPRs
typedef __attribute__((ext_vector_type(8))) unsigned short ushort8v;  // 16B store
typedef __attribute__((ext_vector_type(4))) float float4v;  // MFMA C/D

// fp32 -> bf16 RNE
static __device__ __forceinline__ unsigned short f2bf(float x) {
  union { float f; unsigned u; } c; c.f = x;
  return (unsigned short)((c.u + 0x7FFFu + ((c.u >> 16) & 1u)) >> 16);
}

#define GLOAD_LDS16(g, l)                                           \
  __builtin_amdgcn_global_load_lds(                                 \
      (const __attribute__((address_space(1))) void*)(g),           \
      (__attribute__((address_space(3))) void*)(l), 16, 0, 0)

// ---------------- fused prep (v2) ----------------
// wave-per-row. Blocks [0,2048): support rows 4*blk+wave -> Sb + smag.
// Blocks [2048,2560): input rows -> Ib + partials.
// Lane owns floats [8*lane, 8*lane+8) and [512+8*lane, 512+8*lane+8):
// 4 x float4 loads (16B), 2 x ushort8 stores (16B, unit-stride across wave).
__global__ __launch_bounds__(256) void prep(
    const float* __restrict__ S, const float* __restrict__ I,
    unsigned short* __restrict__ Sb, unsigned short* __restrict__ Ib,
    float* __restrict__ smag, float* __restrict__ partials) {
  const int t = threadIdx.x;
  const int lane = t & 63;
  const int wave = t >> 6;
  const int blk = blockIdx.x;
  const bool isS = blk < 2048;
  const int row = (isS ? blk : blk - 2048) * 4 + wave;
  const float4* s4 = reinterpret_cast<const float4*>((isS ? S : I) + (size_t)row * K_DIM);
  ushort8v* d8 = reinterpret_cast<ushort8v*>((isS ? Sb : Ib) + (size_t)row * K_DIM);

  float4 v[4];
  v[0] = s4[2 * lane];
  v[1] = s4[2 * lane + 1];
  v[2] = s4[128 + 2 * lane];
  v[3] = s4[128 + 2 * lane + 1];

  float ss = 0.f;
  ushort8v o0, o1;
#pragma unroll
  for (int h = 0; h < 2; ++h) {
    const float4 a = v[2 * h], b = v[2 * h + 1];
    ushort8v o;
    o[0] = f2bf(a.x); o[1] = f2bf(a.y); o[2] = f2bf(a.z); o[3] = f2bf(a.w);
    o[4] = f2bf(b.x); o[5] = f2bf(b.y); o[6] = f2bf(b.z); o[7] = f2bf(b.w);
    ss += a.x * a.x + a.y * a.y + a.z * a.z + a.w * a.w;
    ss += b.x * b.x + b.y * b.y + b.z * b.z + b.w * b.w;
    if (h == 0) o0 = o; else o1 = o;
  }
  d8[lane] = o0;
  d8[64 + lane] = o1;

#pragma unroll
  for (int m = 32; m >= 1; m >>= 1) ss += __shfl_xor(ss, m, 64);
  if (lane == 0) {
    if (isS) smag[row] = rsqrtf(fmaxf(ss, 1e-10f));
    else     partials[row] = ss;
  }
}

// ---------------- GEMM: 256^2 prefetch-pipelined 8-phase (R3 sched) ----------------
// BYTE-IDENTICAL to R6 (measured ~42.3us; do not touch this round).
// Phase p: [stage SP][counted VMW (R3 placement)][BARRIER][SGB pin]
//          [ds_reads for p+1 (4 or 8)][setprio1; 16 MFMA on p-1 regs; setprio0]
// vmcnt ledger identical to R3: ph2: VMW(10), ph4: VMW(8), ph6: VMW(10), ph8: VMW(8).
__global__ __launch_bounds__(512, 2) void gemm_bt(
    const unsigned short* __restrict__ A,  // [M, K] bf16 (support)
    const unsigned short* __restrict__ B,  // [N, K] bf16 (input)
    const float* __restrict__ smag,        // [M]
    const float* __restrict__ partials,    // [2048] input-row sumsq partials
    float* __restrict__ C) {               // [M, N]
  __shared__ __align__(16) unsigned short lA[32768];  // 2 buf x 2 half x 8192
  __shared__ __align__(16) unsigned short lB[32768];
  __shared__ float wsum[8];

  const int t = threadIdx.x;     // 0..511
  const int lane = t & 63;
  const int wave = t >> 6;       // 0..7
  const int wr = wave >> 2;      // 0..1  (M half)
  const int wc = wave & 3;       // 0..3  (N quarter)

  // XCD swizzle: 256 blocks, 1/CU. Each XCD: 4 contiguous bm-tiles x 8 bn.
  const int blk = blockIdx.x;
  const int xcd = blk & 7;
  const int slot = blk >> 3;     // 0..31
  const int bm = (xcd * 4 + (slot & 3)) * BM;
  const int bn = (slot >> 2) * BN;

  // Input Frobenius-norm partials reduce. VMW(0) keeps vmcnt queue pure-stage.
  {
    float p = partials[t] + partials[t + 512] + partials[t + 1024] + partials[t + 1536];
#pragma unroll
    for (int m = 32; m >= 1; m >>= 1) p += __shfl_xor(p, m, 64);
    if (lane == 0) wsum[wave] = p;
  }
  asm volatile("s_waitcnt vmcnt(0)" ::: "memory");

  // Staging: thread t covers row-in-load = t>>3; stored chunk t&7 holds
  // logical kc = (t&7)^(row&7)  (XOR swizzle via pre-swizzled global src).
  const int srow = t >> 3;
  const int skc = (t & 7) ^ (srow & 7);
  const unsigned short* gA[4];   // loads j: tile rows [64j, 64j+64)
  const unsigned short* gB[4];
  int aoff[4];                   // LDS wave-uniform dest (shorts), per load j
#pragma unroll
  for (int j = 0; j < 4; ++j) {
    gA[j] = A + (size_t)(bm + j * 64 + srow) * K_DIM + skc * 8;
    gB[j] = B + (size_t)(bn + j * 64 + srow) * K_DIM + skc * 8;
    aoff[j] = (j >> 1) * 8192 + (j & 1) * 4096 + wave * 512;
  }

#define STAGE_A(j, buf) do { GLOAD_LDS16(gA[j], &lA[(buf) * 16384 + aoff[j]]); gA[j] += BK; } while (0)
#define STAGE_B(j, buf) do { GLOAD_LDS16(gB[j], &lB[(buf) * 16384 + aoff[j]]); gB[j] += BK; } while (0)
#define SP1(buf) do { STAGE_B(0, buf); STAGE_B(1, buf); } while (0)  // B rows 0-127
#define SP2(buf) do { STAGE_B(2, buf); STAGE_B(3, buf); } while (0)  // B rows 128-255
#define SP3(buf) do { STAGE_A(0, buf); STAGE_A(2, buf); } while (0)  // A mi 0-3 (both halves)
#define SP4(buf) do { STAGE_A(1, buf); STAGE_A(3, buf); } while (0)  // A mi 4-7 (both halves)

  // Fragment read bases (swizzled layout, 0 conflicts verified R1-R6).
  const int fr = lane & 15;
  const int q = lane >> 4;
  const int pc0 = (q ^ (fr & 7)) * 8;        // k-step s=0 chunk offset (shorts)
  const int pc1 = ((4 + q) ^ (fr & 7)) * 8;  // k-step s=1
  const unsigned short* rA = lA + wr * 8192 + fr * 64;
  const unsigned short* rB = lB + (wc >> 1) * 8192 + ((wc & 1) * 64 + fr) * 64;

  short8 af0[2][2], af1[2][2];   // A frag banks: [m2][s]; odd phases use af0
  short8 bfA[4][2], bfB[4][2];   // B frags per K-tile: [nj][s]
  float4v acc[8][4];
#pragma unroll
  for (int i = 0; i < 8; ++i)
#pragma unroll
    for (int j = 0; j < 4; ++j) acc[i][j] = (float4v)0.0f;

#define BARRIER() __builtin_amdgcn_s_barrier()
#define VMW(n) asm volatile("s_waitcnt vmcnt(" #n ")" ::: "memory")
#define PRIO1() __builtin_amdgcn_s_setprio(1)
#define PRIO0() __builtin_amdgcn_s_setprio(0)
// T19 pin: emit n ds_reads first, then the 16-MFMA cluster.
// LLVM SchedGroupMask: DS_READ=0x100, MFMA=0x8.
#define SGB(n) do {                                                            \
    __builtin_amdgcn_sched_group_barrier(0x100, n, 0);                         \
    __builtin_amdgcn_sched_group_barrier(0x008, 16, 0);                        \
  } while (0)

#define LOADB_LO(bank, buf) do {                                               \
    _Pragma("unroll") for (int nj = 0; nj < 2; ++nj) {                         \
      bank[nj][0] = *reinterpret_cast<const short8*>(rB + (buf) * 16384 + nj * 1024 + pc0); \
      bank[nj][1] = *reinterpret_cast<const short8*>(rB + (buf) * 16384 + nj * 1024 + pc1); \
    } } while (0)

#define LOADB_HI(bank, buf) do {                                               \
    _Pragma("unroll") for (int nj = 2; nj < 4; ++nj) {                         \
      bank[nj][0] = *reinterpret_cast<const short8*>(rB + (buf) * 16384 + nj * 1024 + pc0); \
      bank[nj][1] = *reinterpret_cast<const short8*>(rB + (buf) * 16384 + nj * 1024 + pc1); \
    } } while (0)

#define LOADA(bank, buf, pi) do {                                              \
    _Pragma("unroll") for (int m2 = 0; m2 < 2; ++m2) {                         \
      bank[m2][0] = *reinterpret_cast<const short8*>(rA + (buf) * 16384 + ((pi) * 2 + m2) * 1024 + pc0); \
      bank[m2][1] = *reinterpret_cast<const short8*>(rA + (buf) * 16384 + ((pi) * 2 + m2) * 1024 + pc1); \
    } } while (0)

#define MFMA16(pi, abank, bbank) do {                                          \
    PRIO1();                                                                   \
    _Pragma("unroll") for (int m2 = 0; m2 < 2; ++m2)                           \
    _Pragma("unroll") for (int nj = 0; nj < 4; ++nj) {                         \
      acc[(pi) * 2 + m2][nj] = __builtin_amdgcn_mfma_f32_16x16x32_bf16(        \
          abank[m2][0], bbank[nj][0], acc[(pi) * 2 + m2][nj], 0, 0, 0);        \
      acc[(pi) * 2 + m2][nj] = __builtin_amdgcn_mfma_f32_16x16x32_bf16(        \
          abank[m2][1], bbank[nj][1], acc[(pi) * 2 + m2][nj], 0, 0, 0);        \
    } } while (0)

  // Full iteration (2 K-tiles: buf0 phases 1-4, buf1 phases 5-8).
  // Reads/phase: ph1:8 ph2:4 ph3:4 ph4:8 ph5:8 ph6:4 ph7:4 ph8:8.
#define ITER_F() do {                                                          \
    /* ph1 */ SP4(1);           BARRIER(); SGB(8);                             \
              LOADA(af1, 0, 1); LOADB_HI(bfA, 0); MFMA16(0, af0, bfA);         \
    /* ph2 */ SP1(0); VMW(10);  BARRIER(); SGB(4);                             \
              LOADA(af0, 0, 2); MFMA16(1, af1, bfA);                           \
    /* ph3 */ SP2(0);           BARRIER(); SGB(4);                             \
              LOADA(af1, 0, 3); MFMA16(2, af0, bfA);                           \
    /* ph4 */ SP3(0); VMW(8);   BARRIER(); SGB(8);                             \
              LOADB_LO(bfB, 1); LOADA(af0, 1, 0); MFMA16(3, af1, bfA);         \
    /* ph5 */ SP4(0);           BARRIER(); SGB(8);                             \
              LOADA(af1, 1, 1); LOADB_HI(bfB, 1); MFMA16(0, af0, bfB);         \
    /* ph6 */ SP1(1); VMW(10);  BARRIER(); SGB(4);                             \
              LOADA(af0, 1, 2); MFMA16(1, af1, bfB);                           \
    /* ph7 */ SP2(1);           BARRIER(); SGB(4);                             \
              LOADA(af1, 1, 3); MFMA16(2, af0, bfB);                           \
    /* ph8 */ SP3(1); VMW(8);   BARRIER(); SGB(8);                             \
              LOADB_LO(bfA, 0); LOADA(af0, 0, 0); MFMA16(3, af1, bfB);         \
  } while (0)

  // Tail iteration (T14 buf0, T15 buf1): no next-iter stages; R3 tail drains
  // VMW(8)@ph2, VMW(2)@ph4, VMW(0)@ph6.
#define ITER_T() do {                                                          \
    /* ph1 */ SP4(1);           BARRIER(); SGB(8);                             \
              LOADA(af1, 0, 1); LOADB_HI(bfA, 0); MFMA16(0, af0, bfA);         \
    /* ph2 */ VMW(8);           BARRIER(); SGB(4);                             \
              LOADA(af0, 0, 2); MFMA16(1, af1, bfA);                           \
    /* ph3 */                   BARRIER(); SGB(4);                             \
              LOADA(af1, 0, 3); MFMA16(2, af0, bfA);                           \
    /* ph4 */ VMW(2);           BARRIER(); SGB(8);                             \
              LOADB_LO(bfB, 1); LOADA(af0, 1, 0); MFMA16(3, af1, bfA);         \
    /* ph5 */                   BARRIER(); SGB(8);                             \
              LOADA(af1, 1, 1); LOADB_HI(bfB, 1); MFMA16(0, af0, bfB);         \
    /* ph6 */ VMW(0);           BARRIER(); SGB(4);                             \
              LOADA(af0, 1, 2); MFMA16(1, af1, bfB);                           \
    /* ph7 */                   BARRIER(); SGB(4);                             \
              LOADA(af1, 1, 3); MFMA16(2, af0, bfB);                           \
    /* ph8 */                   BARRIER();                                     \
              MFMA16(3, af1, bfB);                                             \
  } while (0)

  // Prologue (R3): stage T0 fully + T1.{B,A-lo} (14 loads); VMW(6) drains T0;
  // barrier publishes staging + wsum; preload ph1 operands (full bfA).
  SP1(0); SP2(0); SP3(0); SP4(0);   // T0 complete
  SP1(1); SP2(1); SP3(1);           // T1 minus A-hi
  VMW(6);                           // T0 drained; [S1,S2,S3](T1) in flight
  BARRIER();
  LOADB_LO(bfA, 0); LOADB_HI(bfA, 0); LOADA(af0, 0, 0);  // ph1 operands

#pragma unroll 1
  for (int it = 0; it < NITER - 1; ++it) ITER_F();
  ITER_T();

  // Epilogue: C/D layout col = lane&15, row = (lane>>4)*4 + reg
  const float imag = rsqrtf(fmaxf(wsum[0] + wsum[1] + wsum[2] + wsum[3] +
                                  wsum[4] + wsum[5] + wsum[6] + wsum[7], 1e-10f));
#pragma unroll
  for (int mi = 0; mi < 8; ++mi) {
    const int rbase = bm + wr * 128 + mi * 16 + q * 4;
#pragma unroll
    for (int r = 0; r < 4; ++r) {
      const int row = rbase + r;
      const float sc = smag[row] * imag;
      float* crow = C + (size_t)row * N_DIM + bn + wc * 64 + fr;
#pragma unroll
      for (int nj = 0; nj < 4; ++nj) crow[nj * 16] = acc[mi][nj][r] * sc;
    }
  }
}

// ---------------- launch ----------------
extern "C" void kernel_launch(void* const* d_in, const int* in_sizes, int n_in,
                              void* d_out, int out_size, void* d_ws, size_t ws_size,
                              hipStream_t stream) {
  const float* S = (const float*)d_in[0];  // support_set [8192,1024]
  const float* I = (const float*)d_in[1];  // input_image [2048,1024]
  float* out = (float*)d_out;

  // ws layout: Sb bf16 16MB | Ib bf16 4MB | smag 32KB | partials 8KB
  unsigned char* ws = (unsigned char*)d_ws;
  unsigned short* Sb = (unsigned short*)ws;
  unsigned short* Ib = (unsigned short*)(ws + (size_t)M_DIM * K_DIM * 2);
  float* smag = (float*)(ws + (size_t)M_DIM * K_DIM * 2 + (size_t)N_DIM * K_DIM * 2);
  float* partials = smag + M_DIM;

  hipLaunchKernelGGL(prep, dim3(2560), dim3(256), 0, stream,
                     S, I, Sb, Ib, smag, partials);
  hipLaunchKernelGGL(gemm_bt, dim3((M_DIM / BM) * (N_DIM / BN)), dim3(512), 0, stream,
                     Sb, Ib, smag, partials, out);
}